// Round 1
// baseline (324.670 us; speedup 1.0000x reference)
//
#include <hip/hip_runtime.h>

#define Bsz 4
#define Cch 256
#define C8d 32
#define Nsp 4096

typedef _Float16 half8 __attribute__((ext_vector_type(8)));
typedef short short8_t __attribute__((ext_vector_type(8)));
typedef float f32x4 __attribute__((ext_vector_type(4)));
typedef float fl4 __attribute__((ext_vector_type(4)));
typedef unsigned short ushort4v __attribute__((ext_vector_type(4)));

static __device__ __forceinline__ unsigned short f2bf(float f) {
  unsigned u = __builtin_bit_cast(unsigned, f);
  u += 0x7FFFu + ((u >> 16) & 1u);      // round-to-nearest-even (finite, >=0 here)
  return (unsigned short)(u >> 16);
}

// ---------------- Projection: x[b,c,n] -> q,k (f16 [b][n][32]), v (bf16 [b][c][n])
__global__ __launch_bounds__(256) void proj_kernel(
    const float* __restrict__ x,
    const float* __restrict__ wq, const float* __restrict__ bq,
    const float* __restrict__ wk, const float* __restrict__ bk,
    const float* __restrict__ wv, const float* __restrict__ bv,
    _Float16* __restrict__ qh, _Float16* __restrict__ kh,
    unsigned short* __restrict__ vbuf)
{
  int bid  = blockIdx.x;            // 1024 = b(4) x ntile(64) x osplit(4)
  int os   = bid & 3;
  int nt   = (bid >> 2) & 63;
  int b    = bid >> 8;
  int wave = threadIdx.x >> 6;
  int lane = threadIdx.x & 63;
  int n    = nt * 64 + lane;
  const float* xb = x + (size_t)b * Cch * Nsp + n;
  int o_base = os * 80 + wave * 20;   // 20 output channels per wave

  for (int og = 0; og < 20; og += 4) {
    int o0 = o_base + og;
    const float* wrow[4];
    float acc[4];
#pragma unroll
    for (int j = 0; j < 4; ++j) {
      int oj = o0 + j;
      if (oj < 32)      { wrow[j] = wq + oj * 256;        acc[j] = bq[oj]; }
      else if (oj < 64) { wrow[j] = wk + (oj - 32) * 256; acc[j] = bk[oj - 32]; }
      else              { wrow[j] = wv + (oj - 64) * 256; acc[j] = bv[oj - 64]; }
    }
    for (int c = 0; c < 256; c += 4) {
      fl4 w0 = *(const fl4*)(wrow[0] + c);
      fl4 w1 = *(const fl4*)(wrow[1] + c);
      fl4 w2 = *(const fl4*)(wrow[2] + c);
      fl4 w3 = *(const fl4*)(wrow[3] + c);
      float x0 = xb[(size_t)(c + 0) * Nsp];
      float x1 = xb[(size_t)(c + 1) * Nsp];
      float x2 = xb[(size_t)(c + 2) * Nsp];
      float x3 = xb[(size_t)(c + 3) * Nsp];
      acc[0] += w0[0]*x0 + w0[1]*x1 + w0[2]*x2 + w0[3]*x3;
      acc[1] += w1[0]*x0 + w1[1]*x1 + w1[2]*x2 + w1[3]*x3;
      acc[2] += w2[0]*x0 + w2[1]*x1 + w2[2]*x2 + w2[3]*x3;
      acc[3] += w3[0]*x0 + w3[1]*x1 + w3[2]*x2 + w3[3]*x3;
    }
#pragma unroll
    for (int j = 0; j < 4; ++j) {
      int oj = o0 + j;
      if (oj < 32)      qh[((size_t)b * Nsp + n) * 32 + oj]        = (_Float16)acc[j];
      else if (oj < 64) kh[((size_t)b * Nsp + n) * 32 + (oj - 32)] = (_Float16)acc[j];
      else              vbuf[((size_t)b * Cch + (oj - 64)) * Nsp + n] = f2bf(acc[j]);
    }
  }
}

// ---------------- Fused attention: one block per (batch, 64-wide m tile)
// S[n][m] = sum_c q[c,n] k[c,m]; P = exp(S-20); out[c,m] = gamma * (sum_n P v[c,n]) / (sum_n P) + x
__global__ __launch_bounds__(256) void attn_kernel(
    const _Float16* __restrict__ qh, const _Float16* __restrict__ kh,
    const unsigned short* __restrict__ vb, const float* __restrict__ x,
    const float* __restrict__ gamma, float* __restrict__ out)
{
  int bid  = blockIdx.x;                 // 256 blocks
  int xcd  = bid & 7;                    // XCD-aware: batch b -> XCDs {2b,2b+1}, v[b] stays L2-resident
  int slot = bid >> 3;
  int b    = xcd >> 1;
  int mt   = slot + 32 * (xcd & 1);
  int m0   = mt * 64;
  int tid  = threadIdx.x;
  int w    = tid >> 6;
  int lane = tid & 63;
  int l15  = lane & 15, lg = lane >> 4;

  __shared__ __align__(16) unsigned short P_lds[64][72];  // [m][n] bf16, stride 144B
  __shared__ float dpart[4][64];
  __shared__ float denom_s[64];

  const _Float16*      qb    = qh + (size_t)b * Nsp * 32;
  const _Float16*      kb    = kh + (size_t)b * Nsp * 32;
  const unsigned short* vbase = vb + (size_t)b * Cch * Nsp;

  // K B-frags (resident): B[k=c][j=m] -> lane reads kT[m0+16j+l15][lg*8 .. +8]
  half8 kB[4];
#pragma unroll
  for (int j = 0; j < 4; ++j)
    kB[j] = *(const half8*)(kb + (size_t)(m0 + 16 * j + l15) * 32 + lg * 8);

  f32x4 acc[4][4];   // [c16][m16]
#pragma unroll
  for (int i = 0; i < 4; ++i)
#pragma unroll
    for (int j = 0; j < 4; ++j) { acc[i][j][0]=0.f; acc[i][j][1]=0.f; acc[i][j][2]=0.f; acc[i][j][3]=0.f; }

  float dsum[4] = {0.f, 0.f, 0.f, 0.f};

  for (int n0 = 0; n0 < Nsp; n0 += 64) {
    // ---- QK^T : wave w owns rows n0+16w..+16; A = qT rows, B = kB
    half8 qA = *(const half8*)(qb + (size_t)(n0 + 16 * w + l15) * 32 + lg * 8);
    f32x4 S[4];
#pragma unroll
    for (int j = 0; j < 4; ++j) {
      f32x4 z; z[0]=0.f; z[1]=0.f; z[2]=0.f; z[3]=0.f;
      S[j] = __builtin_amdgcn_mfma_f32_16x16x32_f16(qA, kB[j], z, 0, 0, 0);
    }
    // ---- exp(S - 20), denom partials, pack bf16
    ushort4v pb[4];
#pragma unroll
    for (int j = 0; j < 4; ++j) {
#pragma unroll
      for (int r = 0; r < 4; ++r) {
        float p = __expf(S[j][r] - 20.0f);
        dsum[j] += p;
        pb[j][r] = f2bf(p);
      }
    }
    __syncthreads();   // previous PV done reading P_lds
#pragma unroll
    for (int j = 0; j < 4; ++j)
      *(ushort4v*)&P_lds[16 * j + l15][16 * w + lg * 4] = pb[j];  // D rows are 4 consecutive n
    __syncthreads();
    // ---- PV : A = v[c][n] bf16, B = P[n][m] from LDS (b128, k-contiguous)
#pragma unroll
    for (int h = 0; h < 2; ++h) {
      short8_t bP[4];
#pragma unroll
      for (int j = 0; j < 4; ++j)
        bP[j] = *(const short8_t*)&P_lds[16 * j + l15][32 * h + lg * 8];
#pragma unroll
      for (int c16 = 0; c16 < 4; ++c16) {
        short8_t aV = *(const short8_t*)(vbase + (size_t)(64 * w + 16 * c16 + l15) * Nsp
                                         + n0 + 32 * h + lg * 8);
#pragma unroll
        for (int j = 0; j < 4; ++j)
          acc[c16][j] = __builtin_amdgcn_mfma_f32_16x16x32_bf16(aV, bP[j], acc[c16][j], 0, 0, 0);
      }
    }
  }

  // ---- denominator: reduce over lane row-groups, then over waves
#pragma unroll
  for (int j = 0; j < 4; ++j) {
    float d = dsum[j];
    d += __shfl_xor(d, 16);
    d += __shfl_xor(d, 32);
    dsum[j] = d;
  }
  if (lane < 16) {
#pragma unroll
    for (int j = 0; j < 4; ++j) dpart[w][16 * j + lane] = dsum[j];
  }
  __syncthreads();
  if (tid < 64) denom_s[tid] = dpart[0][tid] + dpart[1][tid] + dpart[2][tid] + dpart[3][tid];
  __syncthreads();

  // ---- epilogue: out = gamma * acc/denom + x
  float g = gamma[0];
#pragma unroll
  for (int c16 = 0; c16 < 4; ++c16) {
#pragma unroll
    for (int j = 0; j < 4; ++j) {
      float dn = denom_s[16 * j + l15];
#pragma unroll
      for (int r = 0; r < 4; ++r) {
        int c = 64 * w + 16 * c16 + lg * 4 + r;
        int m = m0 + 16 * j + l15;
        size_t idx = ((size_t)b * Cch + c) * Nsp + m;
        out[idx] = g * (acc[c16][j][r] / dn) + x[idx];
      }
    }
  }
}

extern "C" void kernel_launch(void* const* d_in, const int* in_sizes, int n_in,
                              void* d_out, int out_size, void* d_ws, size_t ws_size,
                              hipStream_t stream) {
  const float* x     = (const float*)d_in[0];
  const float* wq    = (const float*)d_in[1];
  const float* bq    = (const float*)d_in[2];
  const float* wk    = (const float*)d_in[3];
  const float* bk    = (const float*)d_in[4];
  const float* wv    = (const float*)d_in[5];
  const float* bv    = (const float*)d_in[6];
  const float* gamma = (const float*)d_in[7];
  float* out = (float*)d_out;

  char* ws = (char*)d_ws;
  _Float16*       qh = (_Float16*)ws;                      // 1 MB
  _Float16*       kh = (_Float16*)(ws + (1u << 20));       // 1 MB
  unsigned short* vb = (unsigned short*)(ws + (2u << 20)); // 8 MB

  proj_kernel<<<dim3(1024), dim3(256), 0, stream>>>(x, wq, bq, wk, bk, wv, bv, qh, kh, vb);
  attn_kernel<<<dim3(256), dim3(256), 0, stream>>>(qh, kh, vb, x, gamma, out);
}

// Round 2
// 162.640 us; speedup vs baseline: 1.9962x; 1.9962x over previous
//
#include <hip/hip_runtime.h>

#define Bsz 4
#define Cch 256
#define Nsp 4096
#define XT_STRIDE 264   // halves per LDS row: 528 B, 16-B aligned, non-pow2

typedef _Float16 half8 __attribute__((ext_vector_type(8)));
typedef _Float16 half4v __attribute__((ext_vector_type(4)));
typedef short short8_t __attribute__((ext_vector_type(8)));
typedef float f32x4 __attribute__((ext_vector_type(4)));
typedef float fl4 __attribute__((ext_vector_type(4)));
typedef unsigned short ushort4v __attribute__((ext_vector_type(4)));

static __device__ __forceinline__ unsigned short f2bf(float f) {
  unsigned u = __builtin_bit_cast(unsigned, f);
  u += 0x7FFFu + ((u >> 16) & 1u);      // RTNE
  return (unsigned short)(u >> 16);
}

// ---------------- W/bias pre-convert: wq|wk|wv -> Wh f16 [320][256], bias f32 [320]
__global__ __launch_bounds__(256) void wconv_kernel(
    const float* __restrict__ wq, const float* __restrict__ wk, const float* __restrict__ wv,
    const float* __restrict__ bq, const float* __restrict__ bk, const float* __restrict__ bv,
    _Float16* __restrict__ Wh, float* __restrict__ bias)
{
  int t = blockIdx.x * 256 + threadIdx.x;   // 80 blocks -> 20480 threads * 4 elems
  int idx0 = t * 4;
  int o = idx0 >> 8, c = idx0 & 255;
  const float* src = (o < 32) ? (wq + o * 256)
                   : (o < 64) ? (wk + (o - 32) * 256)
                              : (wv + (o - 64) * 256);
  fl4 w4 = *(const fl4*)(src + c);
  half4v h;
#pragma unroll
  for (int j = 0; j < 4; ++j) h[j] = (_Float16)w4[j];
  *(half4v*)(Wh + idx0) = h;
  if (t < 320) bias[t] = (t < 32) ? bq[t] : (t < 64) ? bk[t - 32] : bv[t - 64];
}

// ---------------- Projection GEMM: out[o, n] = Wh[o,:] . x[b,:,n] + bias
// q,k -> f16 [b][n][32]; v -> bf16 [b][c][n]
__global__ __launch_bounds__(256) void proj_kernel(
    const float* __restrict__ x, const _Float16* __restrict__ Wh,
    const float* __restrict__ bias,
    _Float16* __restrict__ qh, _Float16* __restrict__ kh,
    unsigned short* __restrict__ vbuf)
{
  int bid = blockIdx.x;          // 512 = b(4) x nt(128)
  int nt  = bid & 127;
  int b   = bid >> 7;
  int n0  = nt * 32;
  int tid = threadIdx.x;
  int w   = tid >> 6, lane = tid & 63;
  int l15 = lane & 15, lg = lane >> 4;

  __shared__ __align__(16) _Float16 xT[32 * XT_STRIDE];

  const float* xb = x + (size_t)b * Cch * Nsp;

  // stage x[b][:][n0..n0+32) -> xT[n][c] f16 (transpose + downconvert)
  {
    int n = lane & 31, ch = lane >> 5;
#pragma unroll
    for (int i = 0; i < 4; ++i) {
      int c0 = i * 64 + w * 16 + ch * 8;
      half8 hv;
#pragma unroll
      for (int j = 0; j < 8; ++j)
        hv[j] = (_Float16)xb[(size_t)(c0 + j) * Nsp + n0 + n];
      *(half8*)&xT[n * XT_STRIDE + c0] = hv;
    }
  }
  __syncthreads();

  // B-frags resident: wave w -> n-subtile (w&1)*16, o-half (w>>1)
  int nsub = (w & 1) * 16;
  half8 bX[8];
#pragma unroll
  for (int k = 0; k < 8; ++k)
    bX[k] = *(const half8*)&xT[(nsub + l15) * XT_STRIDE + k * 32 + lg * 8];

  int n = n0 + nsub + l15;
  int ot0 = (w >> 1) * 10;
#pragma unroll
  for (int t = 0; t < 10; ++t) {
    int ot = ot0 + t;
    const _Float16* wrow = Wh + (size_t)(ot * 16 + l15) * 256 + lg * 8;
    f32x4 acc; acc[0]=0.f; acc[1]=0.f; acc[2]=0.f; acc[3]=0.f;
#pragma unroll
    for (int k = 0; k < 8; ++k) {
      half8 aW = *(const half8*)(wrow + k * 32);
      acc = __builtin_amdgcn_mfma_f32_16x16x32_f16(aW, bX[k], acc, 0, 0, 0);
    }
    fl4 bs = *(const fl4*)(bias + ot * 16 + lg * 4);
    if (ot < 2) {
      half4v qv;
#pragma unroll
      for (int r = 0; r < 4; ++r) qv[r] = (_Float16)(acc[r] + bs[r]);
      *(half4v*)(qh + ((size_t)b * Nsp + n) * 32 + ot * 16 + lg * 4) = qv;
    } else if (ot < 4) {
      half4v kv;
#pragma unroll
      for (int r = 0; r < 4; ++r) kv[r] = (_Float16)(acc[r] + bs[r]);
      *(half4v*)(kh + ((size_t)b * Nsp + n) * 32 + (ot - 2) * 16 + lg * 4) = kv;
    } else {
      int cv = (ot - 4) * 16 + lg * 4;
#pragma unroll
      for (int r = 0; r < 4; ++r)
        vbuf[((size_t)b * Cch + cv + r) * Nsp + n] = f2bf(acc[r] + bs[r]);
    }
  }
}

// ---------------- Fused attention: one block per (batch, 64-wide m tile)
// S[n][m] = sum_c q[c,n] k[c,m]; P = exp(S-20); out[c,m] = gamma * (sum_n P v[c,n]) / (sum_n P) + x
__global__ __launch_bounds__(256) void attn_kernel(
    const _Float16* __restrict__ qh, const _Float16* __restrict__ kh,
    const unsigned short* __restrict__ vb, const float* __restrict__ x,
    const float* __restrict__ gamma, float* __restrict__ out)
{
  int bid  = blockIdx.x;                 // 256 blocks
  int xcd  = bid & 7;                    // batch b -> XCDs {2b,2b+1}: v[b] stays L2-resident
  int slot = bid >> 3;
  int b    = xcd >> 1;
  int mt   = slot + 32 * (xcd & 1);
  int m0   = mt * 64;
  int tid  = threadIdx.x;
  int w    = tid >> 6;
  int lane = tid & 63;
  int l15  = lane & 15, lg = lane >> 4;

  __shared__ __align__(16) unsigned short P_lds[64][72];  // [m][n] bf16, stride 144B
  __shared__ float dpart[4][64];
  __shared__ float denom_s[64];

  const _Float16*       qb    = qh + (size_t)b * Nsp * 32;
  const _Float16*       kb    = kh + (size_t)b * Nsp * 32;
  const unsigned short* vbase = vb + (size_t)b * Cch * Nsp;

  half8 kB[4];
#pragma unroll
  for (int j = 0; j < 4; ++j)
    kB[j] = *(const half8*)(kb + (size_t)(m0 + 16 * j + l15) * 32 + lg * 8);

  f32x4 acc[4][4];   // [c16][m16]
#pragma unroll
  for (int i = 0; i < 4; ++i)
#pragma unroll
    for (int j = 0; j < 4; ++j) { acc[i][j][0]=0.f; acc[i][j][1]=0.f; acc[i][j][2]=0.f; acc[i][j][3]=0.f; }

  float dsum[4] = {0.f, 0.f, 0.f, 0.f};

  for (int n0 = 0; n0 < Nsp; n0 += 64) {
    half8 qA = *(const half8*)(qb + (size_t)(n0 + 16 * w + l15) * 32 + lg * 8);
    f32x4 S[4];
#pragma unroll
    for (int j = 0; j < 4; ++j) {
      f32x4 z; z[0]=0.f; z[1]=0.f; z[2]=0.f; z[3]=0.f;
      S[j] = __builtin_amdgcn_mfma_f32_16x16x32_f16(qA, kB[j], z, 0, 0, 0);
    }
    ushort4v pb[4];
#pragma unroll
    for (int j = 0; j < 4; ++j) {
#pragma unroll
      for (int r = 0; r < 4; ++r) {
        float p = __expf(S[j][r] - 20.0f);
        dsum[j] += p;
        pb[j][r] = f2bf(p);
      }
    }
    __syncthreads();
#pragma unroll
    for (int j = 0; j < 4; ++j)
      *(ushort4v*)&P_lds[16 * j + l15][16 * w + lg * 4] = pb[j];
    __syncthreads();
#pragma unroll
    for (int h = 0; h < 2; ++h) {
      short8_t bP[4];
#pragma unroll
      for (int j = 0; j < 4; ++j)
        bP[j] = *(const short8_t*)&P_lds[16 * j + l15][32 * h + lg * 8];
#pragma unroll
      for (int c16 = 0; c16 < 4; ++c16) {
        short8_t aV = *(const short8_t*)(vbase + (size_t)(64 * w + 16 * c16 + l15) * Nsp
                                         + n0 + 32 * h + lg * 8);
#pragma unroll
        for (int j = 0; j < 4; ++j)
          acc[c16][j] = __builtin_amdgcn_mfma_f32_16x16x32_bf16(aV, bP[j], acc[c16][j], 0, 0, 0);
      }
    }
  }

#pragma unroll
  for (int j = 0; j < 4; ++j) {
    float d = dsum[j];
    d += __shfl_xor(d, 16);
    d += __shfl_xor(d, 32);
    dsum[j] = d;
  }
  if (lane < 16) {
#pragma unroll
    for (int j = 0; j < 4; ++j) dpart[w][16 * j + lane] = dsum[j];
  }
  __syncthreads();
  if (tid < 64) denom_s[tid] = dpart[0][tid] + dpart[1][tid] + dpart[2][tid] + dpart[3][tid];
  __syncthreads();

  float g = gamma[0];
#pragma unroll
  for (int c16 = 0; c16 < 4; ++c16) {
#pragma unroll
    for (int j = 0; j < 4; ++j) {
      float dn = denom_s[16 * j + l15];
#pragma unroll
      for (int r = 0; r < 4; ++r) {
        int c = 64 * w + 16 * c16 + lg * 4 + r;
        int m = m0 + 16 * j + l15;
        size_t idx = ((size_t)b * Cch + c) * Nsp + m;
        out[idx] = g * (acc[c16][j][r] / dn) + x[idx];
      }
    }
  }
}

extern "C" void kernel_launch(void* const* d_in, const int* in_sizes, int n_in,
                              void* d_out, int out_size, void* d_ws, size_t ws_size,
                              hipStream_t stream) {
  const float* x     = (const float*)d_in[0];
  const float* wq    = (const float*)d_in[1];
  const float* bq    = (const float*)d_in[2];
  const float* wk    = (const float*)d_in[3];
  const float* bk    = (const float*)d_in[4];
  const float* wv    = (const float*)d_in[5];
  const float* bv    = (const float*)d_in[6];
  const float* gamma = (const float*)d_in[7];
  float* out = (float*)d_out;

  char* ws = (char*)d_ws;
  _Float16*       qh   = (_Float16*)ws;                        // 1 MB
  _Float16*       kh   = (_Float16*)(ws + (1u << 20));         // 1 MB
  unsigned short* vb   = (unsigned short*)(ws + (2u << 20));   // 8 MB
  _Float16*       Wh   = (_Float16*)(ws + (10u << 20));        // 160 KB
  float*          bias = (float*)(ws + (10u << 20) + (320u * 256u * 2u));

  wconv_kernel<<<dim3(80), dim3(256), 0, stream>>>(wq, wk, wv, bq, bk, bv, Wh, bias);
  proj_kernel<<<dim3(512), dim3(256), 0, stream>>>(x, Wh, bias, qh, kh, vb);
  attn_kernel<<<dim3(256), dim3(256), 0, stream>>>(qh, kh, vb, x, gamma, out);
}

// Round 3
// 133.892 us; speedup vs baseline: 2.4249x; 1.2147x over previous
//
#include <hip/hip_runtime.h>

#define Bsz 4
#define Cch 256
#define Nsp 4096
#define XT_STRIDE 264   // halves per LDS row: 528 B, 16-B aligned, non-pow2

typedef _Float16 half8 __attribute__((ext_vector_type(8)));
typedef _Float16 half4v __attribute__((ext_vector_type(4)));
typedef short short8_t __attribute__((ext_vector_type(8)));
typedef float f32x4 __attribute__((ext_vector_type(4)));
typedef float fl4 __attribute__((ext_vector_type(4)));
typedef unsigned short ushort4v __attribute__((ext_vector_type(4)));

static __device__ __forceinline__ unsigned short f2bf(float f) {
  unsigned u = __builtin_bit_cast(unsigned, f);
  u += 0x7FFFu + ((u >> 16) & 1u);      // RTNE
  return (unsigned short)(u >> 16);
}

// ---------------- W/bias pre-convert: wq|wk|wv -> Wh f16 [320][256], bias f32 [320]
__global__ __launch_bounds__(256) void wconv_kernel(
    const float* __restrict__ wq, const float* __restrict__ wk, const float* __restrict__ wv,
    const float* __restrict__ bq, const float* __restrict__ bk, const float* __restrict__ bv,
    _Float16* __restrict__ Wh, float* __restrict__ bias)
{
  int t = blockIdx.x * 256 + threadIdx.x;
  int idx0 = t * 4;
  int o = idx0 >> 8, c = idx0 & 255;
  const float* src = (o < 32) ? (wq + o * 256)
                   : (o < 64) ? (wk + (o - 32) * 256)
                              : (wv + (o - 64) * 256);
  fl4 w4 = *(const fl4*)(src + c);
  half4v h;
#pragma unroll
  for (int j = 0; j < 4; ++j) h[j] = (_Float16)w4[j];
  *(half4v*)(Wh + idx0) = h;
  if (t < 320) bias[t] = (t < 32) ? bq[t] : (t < 64) ? bk[t - 32] : bv[t - 64];
}

// ---------------- Projection GEMM: out[o, n] = Wh[o,:] . x[b,:,n] + bias
__global__ __launch_bounds__(256) void proj_kernel(
    const float* __restrict__ x, const _Float16* __restrict__ Wh,
    const float* __restrict__ bias,
    _Float16* __restrict__ qh, _Float16* __restrict__ kh,
    unsigned short* __restrict__ vbuf)
{
  int bid = blockIdx.x;          // 512 = b(4) x nt(128)
  int nt  = bid & 127;
  int b   = bid >> 7;
  int n0  = nt * 32;
  int tid = threadIdx.x;
  int w   = tid >> 6, lane = tid & 63;
  int l15 = lane & 15, lg = lane >> 4;

  __shared__ __align__(16) _Float16 xT[32 * XT_STRIDE];

  const float* xb = x + (size_t)b * Cch * Nsp;

  {
    int n = lane & 31, ch = lane >> 5;
#pragma unroll
    for (int i = 0; i < 4; ++i) {
      int c0 = i * 64 + w * 16 + ch * 8;
      half8 hv;
#pragma unroll
      for (int j = 0; j < 8; ++j)
        hv[j] = (_Float16)xb[(size_t)(c0 + j) * Nsp + n0 + n];
      *(half8*)&xT[n * XT_STRIDE + c0] = hv;
    }
  }
  __syncthreads();

  int nsub = (w & 1) * 16;
  half8 bX[8];
#pragma unroll
  for (int k = 0; k < 8; ++k)
    bX[k] = *(const half8*)&xT[(nsub + l15) * XT_STRIDE + k * 32 + lg * 8];

  int n = n0 + nsub + l15;
  int ot0 = (w >> 1) * 10;
#pragma unroll
  for (int t = 0; t < 10; ++t) {
    int ot = ot0 + t;
    const _Float16* wrow = Wh + (size_t)(ot * 16 + l15) * 256 + lg * 8;
    f32x4 acc; acc[0]=0.f; acc[1]=0.f; acc[2]=0.f; acc[3]=0.f;
#pragma unroll
    for (int k = 0; k < 8; ++k) {
      half8 aW = *(const half8*)(wrow + k * 32);
      acc = __builtin_amdgcn_mfma_f32_16x16x32_f16(aW, bX[k], acc, 0, 0, 0);
    }
    fl4 bs = *(const fl4*)(bias + ot * 16 + lg * 4);
    if (ot < 2) {
      half4v qv;
#pragma unroll
      for (int r = 0; r < 4; ++r) qv[r] = (_Float16)(acc[r] + bs[r]);
      *(half4v*)(qh + ((size_t)b * Nsp + n) * 32 + ot * 16 + lg * 4) = qv;
    } else if (ot < 4) {
      half4v kv;
#pragma unroll
      for (int r = 0; r < 4; ++r) kv[r] = (_Float16)(acc[r] + bs[r]);
      *(half4v*)(kh + ((size_t)b * Nsp + n) * 32 + (ot - 2) * 16 + lg * 4) = kv;
    } else {
      int cv = (ot - 4) * 16 + lg * 4;
#pragma unroll
      for (int r = 0; r < 4; ++r)
        vbuf[((size_t)b * Cch + cv + r) * Nsp + n] = f2bf(acc[r] + bs[r]);
    }
  }
}

// ---------------- Fused attention: 8 waves/block, n-step 128
// QK: wave w owns n-slice [n0+16w, +16).  PV: wave w owns c-stripe [32w, +32).
__global__ __launch_bounds__(512) void attn_kernel(
    const _Float16* __restrict__ qh, const _Float16* __restrict__ kh,
    const unsigned short* __restrict__ vb, const float* __restrict__ x,
    const float* __restrict__ gamma, float* __restrict__ out)
{
  int bid  = blockIdx.x;                 // 256 blocks, 1/CU
  int xcd  = bid & 7;                    // batch b -> XCDs {2b,2b+1}: v[b] L2-resident
  int slot = bid >> 3;
  int b    = xcd >> 1;
  int mt   = slot + 32 * (xcd & 1);
  int m0   = mt * 64;
  int tid  = threadIdx.x;
  int w    = tid >> 6;
  int lane = tid & 63;
  int l15  = lane & 15, lg = lane >> 4;

  __shared__ __align__(16) unsigned short P_lds[64][136];  // [m][n] bf16, 272 B stride
  __shared__ float dpart[8][64];
  __shared__ float denom_s[64];

  const _Float16*       qb    = qh + (size_t)b * Nsp * 32;
  const _Float16*       kb    = kh + (size_t)b * Nsp * 32;
  const unsigned short* vbase = vb + (size_t)b * Cch * Nsp;

  // K B-frags resident (same for all waves): B[k=c][col=m]
  half8 kB[4];
#pragma unroll
  for (int j = 0; j < 4; ++j)
    kB[j] = *(const half8*)(kb + (size_t)(m0 + 16 * j + l15) * 32 + lg * 8);

  f32x4 acc[2][4];   // [c16 within 32-c stripe][m16]
#pragma unroll
  for (int i = 0; i < 2; ++i)
#pragma unroll
    for (int j = 0; j < 4; ++j) { acc[i][j][0]=0.f; acc[i][j][1]=0.f; acc[i][j][2]=0.f; acc[i][j][3]=0.f; }

  float dsum[4] = {0.f, 0.f, 0.f, 0.f};

  for (int n0 = 0; n0 < Nsp; n0 += 128) {
    // ---- QK^T for this wave's 16-n slice
    half8 qA = *(const half8*)(qb + (size_t)(n0 + 16 * w + l15) * 32 + lg * 8);
    f32x4 S[4];
#pragma unroll
    for (int j = 0; j < 4; ++j) {
      f32x4 z; z[0]=0.f; z[1]=0.f; z[2]=0.f; z[3]=0.f;
      S[j] = __builtin_amdgcn_mfma_f32_16x16x32_f16(qA, kB[j], z, 0, 0, 0);
    }
    ushort4v pb[4];
#pragma unroll
    for (int j = 0; j < 4; ++j) {
#pragma unroll
      for (int r = 0; r < 4; ++r) {
        float p = __expf(S[j][r] - 20.0f);
        dsum[j] += p;
        pb[j][r] = f2bf(p);
      }
    }
    __syncthreads();   // previous PV done reading P_lds
#pragma unroll
    for (int j = 0; j < 4; ++j)
      *(ushort4v*)&P_lds[16 * j + l15][16 * w + lg * 4] = pb[j];  // D rows = 4 consecutive n
    __syncthreads();
    // ---- PV over this wave's 32-c stripe
    __builtin_amdgcn_s_setprio(1);
#pragma unroll
    for (int k = 0; k < 4; ++k) {      // 32-n k-chunks within the 128-n block
      short8_t bP[4];
#pragma unroll
      for (int j = 0; j < 4; ++j)
        bP[j] = *(const short8_t*)&P_lds[16 * j + l15][k * 32 + lg * 8];
#pragma unroll
      for (int c16 = 0; c16 < 2; ++c16) {
        short8_t aV = *(const short8_t*)(vbase + (size_t)(32 * w + 16 * c16 + l15) * Nsp
                                         + n0 + k * 32 + lg * 8);
#pragma unroll
        for (int j = 0; j < 4; ++j)
          acc[c16][j] = __builtin_amdgcn_mfma_f32_16x16x32_bf16(aV, bP[j], acc[c16][j], 0, 0, 0);
      }
    }
    __builtin_amdgcn_s_setprio(0);
  }

  // ---- denominator: lane-group reduce, then across 8 waves
#pragma unroll
  for (int j = 0; j < 4; ++j) {
    float d = dsum[j];
    d += __shfl_xor(d, 16);
    d += __shfl_xor(d, 32);
    dsum[j] = d;
  }
  if (lane < 16) {
#pragma unroll
    for (int j = 0; j < 4; ++j) dpart[w][16 * j + lane] = dsum[j];
  }
  __syncthreads();
  if (tid < 64) {
    float s = 0.f;
#pragma unroll
    for (int ww = 0; ww < 8; ++ww) s += dpart[ww][tid];
    denom_s[tid] = s;
  }
  __syncthreads();

  // ---- epilogue
  float g = gamma[0];
#pragma unroll
  for (int c16 = 0; c16 < 2; ++c16) {
#pragma unroll
    for (int j = 0; j < 4; ++j) {
      float dn = denom_s[16 * j + l15];
#pragma unroll
      for (int r = 0; r < 4; ++r) {
        int c = 32 * w + 16 * c16 + lg * 4 + r;
        int m = m0 + 16 * j + l15;
        size_t idx = ((size_t)b * Cch + c) * Nsp + m;
        out[idx] = g * (acc[c16][j][r] / dn) + x[idx];
      }
    }
  }
}

extern "C" void kernel_launch(void* const* d_in, const int* in_sizes, int n_in,
                              void* d_out, int out_size, void* d_ws, size_t ws_size,
                              hipStream_t stream) {
  const float* x     = (const float*)d_in[0];
  const float* wq    = (const float*)d_in[1];
  const float* bq    = (const float*)d_in[2];
  const float* wk    = (const float*)d_in[3];
  const float* bk    = (const float*)d_in[4];
  const float* wv    = (const float*)d_in[5];
  const float* bv    = (const float*)d_in[6];
  const float* gamma = (const float*)d_in[7];
  float* out = (float*)d_out;

  char* ws = (char*)d_ws;
  _Float16*       qh   = (_Float16*)ws;                        // 1 MB
  _Float16*       kh   = (_Float16*)(ws + (1u << 20));         // 1 MB
  unsigned short* vb   = (unsigned short*)(ws + (2u << 20));   // 8 MB
  _Float16*       Wh   = (_Float16*)(ws + (10u << 20));        // 160 KB
  float*          bias = (float*)(ws + (10u << 20) + (320u * 256u * 2u));

  wconv_kernel<<<dim3(80), dim3(256), 0, stream>>>(wq, wk, wv, bq, bk, bv, Wh, bias);
  proj_kernel<<<dim3(512), dim3(256), 0, stream>>>(x, Wh, bias, qh, kh, vb);
  attn_kernel<<<dim3(256), dim3(512), 0, stream>>>(qh, kh, vb, x, gamma, out);
}